// Round 12
// baseline (779.758 us; speedup 1.0000x reference)
//
#include <hip/hip_runtime.h>

typedef unsigned short u16;
typedef __attribute__((ext_vector_type(8))) short bf16x8;
typedef __attribute__((ext_vector_type(4))) float f32x4;
typedef __attribute__((ext_vector_type(4))) u16 u16x4;
typedef __attribute__((ext_vector_type(8))) u16 u16x8;

#define MFMA16(a, b, c) __builtin_amdgcn_mfma_f32_16x16x32_bf16(a, b, c, 0, 0, 0)

__device__ __forceinline__ u16 f2bf(float f) {
    union { float f; unsigned u; } v; v.f = f;
    unsigned r = (v.u + 0x7FFFu + ((v.u >> 16) & 1u)) >> 16;  // RNE
    return (u16)r;
}

// ---------- prep: fp32 -> bf16 (optionally scaled) ----------
__global__ __launch_bounds__(256) void cvt_kernel(const float* __restrict__ src,
                                                  u16* __restrict__ dst, int n4, float scale) {
    int i = blockIdx.x * 256 + threadIdx.x;
    if (i >= n4) return;
    f32x4 v = *(const f32x4*)(src + (size_t)i * 4);
    u16x4 o;
#pragma unroll
    for (int j = 0; j < 4; ++j) o[j] = f2bf(v[j] * scale);
    *(u16x4*)(dst + (size_t)i * 4) = o;
}

// ---------- prep: V (8192x512 f32) -> Vt (512x8192 bf16) ----------
__global__ __launch_bounds__(256) void prep_vt(const float* __restrict__ V, u16* __restrict__ Vt) {
    __shared__ float tile[64][65];
    int t = threadIdx.x;
    int n0 = blockIdx.x * 64;
    int d0 = blockIdx.y * 64;
    int tr = t >> 4, tc = t & 15;
#pragma unroll
    for (int p = 0; p < 4; ++p) {
        int n = p * 16 + tr;
        f32x4 v = *(const f32x4*)(V + (size_t)(n0 + n) * 512 + d0 + tc * 4);
#pragma unroll
        for (int j = 0; j < 4; ++j) tile[n][tc * 4 + j] = v[j];
    }
    __syncthreads();
#pragma unroll
    for (int p = 0; p < 4; ++p) {
        int d = p * 16 + tr;
        u16x4 o;
#pragma unroll
        for (int j = 0; j < 4; ++j) o[j] = f2bf(tile[tc * 4 + j][d]);
        *(u16x4*)(Vt + (size_t)(d0 + d) * 8192 + n0 + tc * 4) = o;
    }
}

__global__ __launch_bounds__(256) void zero_kernel(float* __restrict__ p, int n) {
    int i = blockIdx.x * 256 + threadIdx.x;
    if (i < n) p[i] = 0.f;
}

// ======= GEMM1: P = exp(Qs . Kb^T), l += rowsums. Barrier-free main loop. =======
// 4096 blocks: XCD x owns keys [x*1024,+1024) (Kb panel 1MB, L2-resident).
// 256 thr / 4 waves (2wr x 2wc), wave 64x64; A,B fragments direct from global (L1/L2).
__global__ __launch_bounds__(256) void gemm1_kernel(const u16* __restrict__ Qs,
                                                    const u16* __restrict__ Kb,
                                                    u16* __restrict__ P,
                                                    float* __restrict__ l) {
    __shared__ __align__(16) u16 smem[32768];  // 64 KB bounce (epilogue only)
    const int tid = threadIdx.x;
    const int wid = tid >> 6;
    const int lane = tid & 63;
    const int lo = lane & 15;
    const int hi = lane >> 4;
    const int wr = wid >> 1, wc = wid & 1;

    const int bid = blockIdx.x;
    const int x = bid & 7, g = bid >> 3;
    const int m0 = (g >> 3) * 128;
    const int n0 = (x * 8 + (g & 7)) * 128;

    const u16* ap[4];
    const u16* bp[4];
#pragma unroll
    for (int t = 0; t < 4; ++t) {
        ap[t] = Qs + (size_t)(m0 + wr * 64 + t * 16 + lo) * 512 + hi * 8;
        bp[t] = Kb + (size_t)(n0 + wc * 64 + t * 16 + lo) * 512 + hi * 8;
    }

    f32x4 acc[4][4];
#pragma unroll
    for (int a = 0; a < 4; ++a)
#pragma unroll
        for (int b = 0; b < 4; ++b) acc[a][b] = (f32x4){0.f, 0.f, 0.f, 0.f};

#pragma unroll
    for (int s = 0; s < 8; ++s) {
        bf16x8 af[4][2], bf[4][2];
#pragma unroll
        for (int t = 0; t < 4; ++t) {
            af[t][0] = *(const bf16x8*)(ap[t] + s * 64);
            af[t][1] = *(const bf16x8*)(ap[t] + s * 64 + 32);
            bf[t][0] = *(const bf16x8*)(bp[t] + s * 64);
            bf[t][1] = *(const bf16x8*)(bp[t] + s * 64 + 32);
        }
#pragma unroll
        for (int kk = 0; kk < 2; ++kk)
#pragma unroll
            for (int mt = 0; mt < 4; ++mt)
#pragma unroll
                for (int nt = 0; nt < 4; ++nt)
                    acc[mt][nt] = MFMA16(af[mt][kk], bf[nt][kk], acc[mt][nt]);
    }

    // ---- epilogue (R11-verified): exp; rowsum -> atomicAdd; LDS bounce -> P store ----
#pragma unroll
    for (int mt = 0; mt < 4; ++mt)
#pragma unroll
        for (int nt = 0; nt < 4; ++nt)
#pragma unroll
            for (int r = 0; r < 4; ++r) acc[mt][nt][r] = __expf(acc[mt][nt][r]);

#pragma unroll
    for (int mt = 0; mt < 4; ++mt)
#pragma unroll
        for (int r = 0; r < 4; ++r) {
            float rs = acc[mt][0][r] + acc[mt][1][r] + acc[mt][2][r] + acc[mt][3][r];
            rs += __shfl_xor(rs, 1);
            rs += __shfl_xor(rs, 2);
            rs += __shfl_xor(rs, 4);
            rs += __shfl_xor(rs, 8);
            if (lo == 0) atomicAdd(&l[m0 + wr * 64 + mt * 16 + 4 * hi + r], rs);
        }

    __syncthreads();
#pragma unroll
    for (int mt = 0; mt < 4; ++mt)
#pragma unroll
        for (int nt = 0; nt < 4; ++nt)
#pragma unroll
            for (int r = 0; r < 4; ++r) {
                int row = wr * 64 + mt * 16 + 4 * hi + r;
                int col = wc * 64 + nt * 16 + lo;
                int c16 = col >> 3;
                int sw = (c16 & 8) | ((c16 ^ row) & 7);
                smem[row * 128 + sw * 8 + (col & 7)] = f2bf(acc[mt][nt][r]);
            }
    __syncthreads();
    {
        int row = tid >> 1, half = tid & 1;
        u16* dst = P + (size_t)(m0 + row) * 8192 + n0 + half * 64;
#pragma unroll
        for (int c = 0; c < 8; ++c) {
            int c16 = half * 8 + c;
            int sw = (c16 & 8) | ((c16 ^ row) & 7);
            *(u16x8*)(dst + c * 8) = *(const u16x8*)(smem + row * 128 + sw * 8);
        }
    }
}

// ======= GEMM2: out = (P . V) / l. No LDS, no barriers. =======
// 512 blocks: bn = xcd&3 (Vt panel 2MB L2-resident per XCD), bm = (xcd>>2)*64 + (bid>>3).
// 512 thr / 8 waves (2wr x 4wc), wave 32x32, tile 64x128; P rows stream from L3;
// intra-block 4x P-row duplication absorbed by L1 (8KB/step working set).
__global__ __launch_bounds__(512) void gemm2_kernel(const u16* __restrict__ P,
                                                    const u16* __restrict__ Vt,
                                                    const float* __restrict__ l,
                                                    float* __restrict__ out) {
    const int tid = threadIdx.x;
    const int wid = tid >> 6;
    const int lane = tid & 63;
    const int lo = lane & 15;
    const int hi = lane >> 4;
    const int wr = wid >> 2, wc = wid & 3;

    const int bid = blockIdx.x;
    const int x = bid & 7, g = bid >> 3;  // g in 0..63
    const int bn = x & 3;
    const int bm = (x >> 2) * 64 + g;     // 0..127 (64-row tiles); bijective
    const int m0 = bm * 64, n0 = bn * 128;

    const u16* ap[2];
    const u16* bp[2];
#pragma unroll
    for (int t = 0; t < 2; ++t) {
        ap[t] = P + (size_t)(m0 + wr * 32 + t * 16 + lo) * 8192 + hi * 8;
        bp[t] = Vt + (size_t)(n0 + wc * 32 + t * 16 + lo) * 8192 + hi * 8;
    }

    f32x4 acc[2][2];
#pragma unroll
    for (int a = 0; a < 2; ++a)
#pragma unroll
        for (int b = 0; b < 2; ++b) acc[a][b] = (f32x4){0.f, 0.f, 0.f, 0.f};

#pragma unroll 2
    for (int s = 0; s < 128; ++s) {
        bf16x8 af[2][2], bf[2][2];
#pragma unroll
        for (int t = 0; t < 2; ++t) {
            af[t][0] = *(const bf16x8*)(ap[t] + s * 64);
            af[t][1] = *(const bf16x8*)(ap[t] + s * 64 + 32);
            bf[t][0] = *(const bf16x8*)(bp[t] + s * 64);
            bf[t][1] = *(const bf16x8*)(bp[t] + s * 64 + 32);
        }
#pragma unroll
        for (int kk = 0; kk < 2; ++kk)
#pragma unroll
            for (int mt = 0; mt < 2; ++mt)
#pragma unroll
                for (int nt = 0; nt < 2; ++nt)
                    acc[mt][nt] = MFMA16(af[mt][kk], bf[nt][kk], acc[mt][nt]);
    }

    // ---- epilogue: scale by 1/l[row], f32 store (lo-contiguous cols) ----
#pragma unroll
    for (int mt = 0; mt < 2; ++mt)
#pragma unroll
        for (int r = 0; r < 4; ++r) {
            int row = m0 + wr * 32 + mt * 16 + 4 * hi + r;
            float inv = 1.0f / l[row];
            float* orow = out + (size_t)row * 512 + n0 + wc * 32 + lo;
            orow[0] = acc[mt][0][r] * inv;
            orow[16] = acc[mt][1][r] * inv;
        }
}

extern "C" void kernel_launch(void* const* d_in, const int* in_sizes, int n_in,
                              void* d_out, int out_size, void* d_ws, size_t ws_size,
                              hipStream_t stream) {
    const float* Q = (const float*)d_in[0];
    const float* K = (const float*)d_in[1];
    const float* V = (const float*)d_in[2];
    float* out = (float*)d_out;
    char* ws = (char*)d_ws;

    const float scale = 0.08838834764831845f;  // 2/sqrt(512): softmax(s)^2 renorm == softmax(2s)

    // ws layout: Qs 8M | Kb 8M | Vt 8M (@16M) | l 64K (@24M) | P 128M (@24M+64K)
    u16* Qs = (u16*)(ws + 0);
    u16* Kb = (u16*)(ws + 8388608);
    u16* Vt = (u16*)(ws + 16777216);
    float* lsum = (float*)(ws + 25165824);
    u16* P = (u16*)(ws + 25165824 + 65536);

    cvt_kernel<<<4096, 256, 0, stream>>>(Q, Qs, 1048576, scale);
    cvt_kernel<<<4096, 256, 0, stream>>>(K, Kb, 1048576, 1.0f);
    prep_vt<<<dim3(128, 8), 256, 0, stream>>>(V, Vt);
    zero_kernel<<<32, 256, 0, stream>>>(lsum, 8192);
    gemm1_kernel<<<4096, 256, 0, stream>>>(Qs, Kb, P, lsum);
    gemm2_kernel<<<512, 512, 0, stream>>>(P, Vt, lsum, out);
}

// Round 13
// 464.354 us; speedup vs baseline: 1.6792x; 1.6792x over previous
//
#include <hip/hip_runtime.h>

typedef unsigned short u16;
typedef __attribute__((ext_vector_type(8))) short bf16x8;
typedef __attribute__((ext_vector_type(4))) float f32x4;
typedef __attribute__((ext_vector_type(4))) u16 u16x4;

#define MFMA16(a, b, c) __builtin_amdgcn_mfma_f32_16x16x32_bf16(a, b, c, 0, 0, 0)

__device__ __forceinline__ u16 f2bf(float f) {
    union { float f; unsigned u; } v; v.f = f;
    unsigned r = (v.u + 0x7FFFu + ((v.u >> 16) & 1u)) >> 16;  // RNE
    return (u16)r;
}

__device__ __forceinline__ void gload_lds16(const void* g, void* l) {
    __builtin_amdgcn_global_load_lds((const __attribute__((address_space(1))) void*)g,
                                     (__attribute__((address_space(3))) void*)l, 16, 0, 0);
}

// ---------- prep: fp32 -> bf16 (optionally scaled) ----------
__global__ __launch_bounds__(256) void cvt_kernel(const float* __restrict__ src,
                                                  u16* __restrict__ dst, int n4, float scale) {
    int i = blockIdx.x * 256 + threadIdx.x;
    if (i >= n4) return;
    f32x4 v = *(const f32x4*)(src + (size_t)i * 4);
    u16x4 o;
#pragma unroll
    for (int j = 0; j < 4; ++j) o[j] = f2bf(v[j] * scale);
    *(u16x4*)(dst + (size_t)i * 4) = o;
}

// ---------- prep: V (8192x512 f32) -> Vt (512x8192 bf16) ----------
__global__ __launch_bounds__(256) void prep_vt(const float* __restrict__ V, u16* __restrict__ Vt) {
    __shared__ float tile[64][65];
    int t = threadIdx.x;
    int n0 = blockIdx.x * 64;
    int d0 = blockIdx.y * 64;
    int tr = t >> 4, tc = t & 15;
#pragma unroll
    for (int p = 0; p < 4; ++p) {
        int n = p * 16 + tr;
        f32x4 v = *(const f32x4*)(V + (size_t)(n0 + n) * 512 + d0 + tc * 4);
#pragma unroll
        for (int j = 0; j < 4; ++j) tile[n][tc * 4 + j] = v[j];
    }
    __syncthreads();
#pragma unroll
    for (int p = 0; p < 4; ++p) {
        int d = p * 16 + tr;
        u16x4 o;
#pragma unroll
        for (int j = 0; j < 4; ++j) o[j] = f2bf(tile[tc * 4 + j][d]);
        *(u16x4*)(Vt + (size_t)(d0 + d) * 8192 + n0 + tc * 4) = o;
    }
}

// ---------- flash attention: BM=64, KVBLK=64, key-split 2, 16 waves, 1 barrier/iter ----------
// R10 schedule, re-partitioned for 4 waves/SIMD: 16 waves = 4 row-strips x 4 key-strips(16).
// Per-wave regs: qf 64 + o 32 + vb 16 -> fits 128-VGPR budget of 4 waves/SIMD.
__global__ __launch_bounds__(1024) void flash_kernel(
    const u16* __restrict__ Qs, const u16* __restrict__ Kb, const u16* __restrict__ Vt,
    float* __restrict__ Opart, float* __restrict__ lpart) {
    __shared__ __align__(16) u16 lds_k[2][64 * 512];  // 128 KB, 16B-chunk XOR swizzle
    __shared__ __align__(16) u16 lds_p[2][64 * 64];   // 16 KB P ping-pong, swizzled
    __shared__ float s_l[4][64];

    const int tid = threadIdx.x;
    const int wid = tid >> 6;   // 0..15
    const int lane = tid & 63;
    const int lo = lane & 15;
    const int hi = lane >> 4;
    const int mi = wid >> 2;    // row strip (4 x 16 rows)
    const int nj = wid & 3;     // key strip (4 x 16 keys)

    // same-XCD blocks share a key-split (L2 reuse of the K/V stream)
    const int bx = blockIdx.x;
    const int x = bx & 7;
    const int g = bx >> 3;
    const int ks = x >> 2;
    const int mtile = g * 4 + (x & 3);
    const int key0 = ks * 4096;

    // Q fragments (B-operand of swapped S-MFMA): 16 rows, col=lo, k=hi*8+j per kt. 64 VGPR.
    bf16x8 qf[16];
    {
        const u16* qrow = Qs + (size_t)(mtile * 64 + mi * 16 + lo) * 512 + hi * 8;
#pragma unroll
        for (int kt = 0; kt < 16; ++kt) qf[kt] = *(const bf16x8*)(qrow + kt * 32);
    }

    f32x4 o[4][2];  // 64 rows x 32 dv cols (wave owns cols [wid*32, +32))
#pragma unroll
    for (int a = 0; a < 4; ++a)
#pragma unroll
        for (int b = 0; b < 2; ++b) o[a][b] = (f32x4){0.f, 0.f, 0.f, 0.f};
    float lsum = 0.f;
    bf16x8 vb[2][2];  // V frags for tile t, consumed by PV at iter t+1

    // S-read addressing (verified): chunk(kt) = (kt*4+hi) ^ (krow&7), krow = nj*16+lo
    // (nj*16 is 0 mod 8, so krow&7 == lo&7 and the cbase decomposition is unchanged)
    const int cbase = ((hi ^ (lo & 3)) + ((lo >> 2) & 1) * 4) * 8;
    const int rowA = (nj * 16 + lo) * 512;

    // P-write: row = mi*16+lo; wave's keys nj*16 + 4*hi + r -> chunk16 nj*2+(hi>>1), XOR row&7
    const int qrow = mi * 16 + lo;
    const int pw = qrow * 64 + ((((nj << 1) + (hi >> 1)) ^ (qrow & 7)) << 3) + (hi & 1) * 4;

#define STAGE_K(IT, BUF)                                                            \
    {                                                                               \
        const u16* kb_ = Kb + (size_t)(key0 + (IT) * 64) * 512;                     \
        _Pragma("unroll") for (int r4_ = 0; r4_ < 4; ++r4_) {                       \
            int row_ = (wid << 2) + r4_;                                            \
            gload_lds16(kb_ + (size_t)row_ * 512 + ((lane ^ (row_ & 7)) << 3),      \
                        &lds_k[BUF][row_ * 512]);                                   \
        }                                                                           \
    }

// wave's 16 keys x 16 rows over K=512: 2 indep chains of 8
#define S_COMPUTE(BUF, SE, SO)                                                      \
    {                                                                               \
        const u16* pAe = &lds_k[BUF][0] + rowA + cbase;                             \
        const u16* pAo = &lds_k[BUF][0] + rowA + (cbase ^ 32);                      \
        _Pragma("unroll") for (int kt2 = 0; kt2 < 8; ++kt2) {                       \
            bf16x8 ae = *(const bf16x8*)(pAe + kt2 * 64);                           \
            bf16x8 ao = *(const bf16x8*)(pAo + kt2 * 64);                           \
            SE = MFMA16(ae, qf[2 * kt2], SE);                                       \
            SO = MFMA16(ao, qf[2 * kt2 + 1], SO);                                   \
        }                                                                           \
    }

#define PV_STEP(PBUF)                                                               \
    {                                                                               \
        _Pragma("unroll") for (int mt = 0; mt < 4; ++mt) {                          \
            int m = mt * 16 + lo;                                                   \
            int c0 = hi ^ (m & 7);                                                  \
            int c1 = (4 + hi) ^ (m & 7);                                            \
            bf16x8 pa0 = *(const bf16x8*)(&lds_p[PBUF][m * 64 + c0 * 8]);           \
            bf16x8 pa1 = *(const bf16x8*)(&lds_p[PBUF][m * 64 + c1 * 8]);           \
            _Pragma("unroll") for (int nt = 0; nt < 2; ++nt) {                      \
                f32x4 c_ = o[mt][nt];                                               \
                c_ = MFMA16(pa0, vb[nt][0], c_);                                    \
                c_ = MFMA16(pa1, vb[nt][1], c_);                                    \
                o[mt][nt] = c_;                                                     \
            }                                                                       \
        }                                                                           \
    }

#define EXP_PW(S, PBUF)                                                             \
    {                                                                               \
        u16x4 w;                                                                    \
        _Pragma("unroll") for (int r = 0; r < 4; ++r) {                             \
            float p = __expf((S)[r]);                                               \
            lsum += p;                                                              \
            w[r] = f2bf(p);                                                         \
        }                                                                           \
        *(u16x4*)(&lds_p[PBUF][pw]) = w;                                            \
    }

#define VB_LOAD(T)                                                                  \
    {                                                                               \
        _Pragma("unroll") for (int nt = 0; nt < 2; ++nt) {                          \
            const u16* vrow = Vt + (size_t)(wid * 32 + nt * 16 + lo) * 8192 +       \
                              key0 + (T) * 64 + hi * 8;                             \
            vb[nt][0] = *(const bf16x8*)(vrow);                                     \
            vb[nt][1] = *(const bf16x8*)(vrow + 32);                                \
        }                                                                           \
    }

    // prologue: K(0) -> buf0
    STAGE_K(0, 0)
    asm volatile("s_waitcnt vmcnt(0)\n\ts_barrier" ::: "memory");

    // iter 0: no PV yet
    {
        STAGE_K(1, 1)
        f32x4 se = {0.f, 0.f, 0.f, 0.f}, so = se;
        VB_LOAD(0)
        __builtin_amdgcn_s_setprio(1);
        S_COMPUTE(0, se, so)
        __builtin_amdgcn_s_setprio(0);
        f32x4 s = se + so;
        EXP_PW(s, 0)
        asm volatile("s_waitcnt vmcnt(0) lgkmcnt(0)\n\ts_barrier" ::: "memory");
    }

    for (int t = 1; t < 64; ++t) {
        const int cur = t & 1;
        if (t < 63) STAGE_K(t + 1, cur ^ 1)
        // PV(t-1) first: consumes vb (loaded iter t-1) + lds_p[cur^1], both ready
        __builtin_amdgcn_s_setprio(1);
        PV_STEP(cur ^ 1)
        __builtin_amdgcn_s_setprio(0);
        // V(t): overwrite vb after PV consumed it; lands under S(t)
        VB_LOAD(t)
        f32x4 se = {0.f, 0.f, 0.f, 0.f}, so = se;
        __builtin_amdgcn_s_setprio(1);
        S_COMPUTE(cur, se, so)
        __builtin_amdgcn_s_setprio(0);
        f32x4 s = se + so;
        EXP_PW(s, cur)
        asm volatile("s_waitcnt vmcnt(0) lgkmcnt(0)\n\ts_barrier" ::: "memory");
    }

    // epilogue PV for tile 63 (P in lds_p[1], vb holds V(63))
    __builtin_amdgcn_s_setprio(1);
    PV_STEP(1)
    __builtin_amdgcn_s_setprio(0);

    // ---- epilogue: lsum covers wave's 16 keys for qrow; reduce over hi lanes ----
    lsum += __shfl_xor(lsum, 16);
    lsum += __shfl_xor(lsum, 32);
    if (lane < 16) s_l[nj][qrow] = lsum;
    __syncthreads();

    const int lb = mtile * 2 + ks;  // logical partial index
    {
        float* Ob = Opart + (size_t)lb * (64 * 512);
#pragma unroll
        for (int mt = 0; mt < 4; ++mt)
#pragma unroll
            for (int nt = 0; nt < 2; ++nt)
#pragma unroll
                for (int r = 0; r < 4; ++r) {
                    int row = mt * 16 + hi * 4 + r;
                    int col = wid * 32 + nt * 16 + lo;
                    Ob[row * 512 + col] = o[mt][nt][r];
                }
        if (tid < 64) {
            lpart[lb * 64 + tid] = s_l[0][tid] + s_l[1][tid] + s_l[2][tid] + s_l[3][tid];
        }
    }
}

// ---------- combine the 2 key-split partials: out = (O0+O1)/(l0+l1) ----------
__global__ __launch_bounds__(256) void combine_kernel(const float* __restrict__ Opart,
                                                      const float* __restrict__ lpart,
                                                      float* __restrict__ out) {
    int i = blockIdx.x * 256 + threadIdx.x;  // float4 index; 8192*512/4 = 1048576 total
    int row = i >> 7;
    int c4 = i & 127;
    int mtile = row >> 6, rl = row & 63;
    int b0 = mtile * 2, b1 = b0 + 1;
    float inv = 1.0f / (lpart[b0 * 64 + rl] + lpart[b1 * 64 + rl]);
    f32x4 a = *(const f32x4*)(Opart + (size_t)b0 * 32768 + rl * 512 + c4 * 4);
    f32x4 b = *(const f32x4*)(Opart + (size_t)b1 * 32768 + rl * 512 + c4 * 4);
    f32x4 r = (a + b) * inv;
    *(f32x4*)(out + (size_t)row * 512 + c4 * 4) = r;
}

extern "C" void kernel_launch(void* const* d_in, const int* in_sizes, int n_in,
                              void* d_out, int out_size, void* d_ws, size_t ws_size,
                              hipStream_t stream) {
    const float* Q = (const float*)d_in[0];
    const float* K = (const float*)d_in[1];
    const float* V = (const float*)d_in[2];
    float* out = (float*)d_out;
    char* ws = (char*)d_ws;

    // ws layout (bytes): Qs 8M | Kb 8M | Vt 8M | Opart 32M | lpart 64K
    u16* Qs = (u16*)(ws + 0);
    u16* Kb = (u16*)(ws + 8388608);
    u16* Vt = (u16*)(ws + 16777216);
    float* Op = (float*)(ws + 25165824);
    float* lp = (float*)(ws + 58720256);

    const float scale = 0.08838834764831845f;  // 2 / sqrt(512): softmax(s)^2 renorm == softmax(2s)
    cvt_kernel<<<4096, 256, 0, stream>>>(Q, Qs, 1048576, scale);
    cvt_kernel<<<4096, 256, 0, stream>>>(K, Kb, 1048576, 1.0f);
    prep_vt<<<dim3(128, 8), 256, 0, stream>>>(V, Vt);
    flash_kernel<<<256, 1024, 0, stream>>>(Qs, Kb, Vt, Op, lp);
    combine_kernel<<<4096, 256, 0, stream>>>(Op, lp, out);
}

// Round 14
// 256.166 us; speedup vs baseline: 3.0440x; 1.8127x over previous
//
#include <hip/hip_runtime.h>

typedef unsigned short u16;
typedef __attribute__((ext_vector_type(8))) short bf16x8;
typedef __attribute__((ext_vector_type(4))) float f32x4;
typedef __attribute__((ext_vector_type(4))) u16 u16x4;

#define MFMA16(a, b, c) __builtin_amdgcn_mfma_f32_16x16x32_bf16(a, b, c, 0, 0, 0)

__device__ __forceinline__ u16 f2bf(float f) {
    union { float f; unsigned u; } v; v.f = f;
    unsigned r = (v.u + 0x7FFFu + ((v.u >> 16) & 1u)) >> 16;  // RNE
    return (u16)r;
}

__device__ __forceinline__ void gload_lds16(const void* g, void* l) {
    __builtin_amdgcn_global_load_lds((const __attribute__((address_space(1))) void*)g,
                                     (__attribute__((address_space(3))) void*)l, 16, 0, 0);
}

// ---------- prep: fp32 -> bf16 (optionally scaled) ----------
__global__ __launch_bounds__(256) void cvt_kernel(const float* __restrict__ src,
                                                  u16* __restrict__ dst, int n4, float scale) {
    int i = blockIdx.x * 256 + threadIdx.x;
    if (i >= n4) return;
    f32x4 v = *(const f32x4*)(src + (size_t)i * 4);
    u16x4 o;
#pragma unroll
    for (int j = 0; j < 4; ++j) o[j] = f2bf(v[j] * scale);
    *(u16x4*)(dst + (size_t)i * 4) = o;
}

// ---------- prep: V (8192x512 f32) -> Vt (512x8192 bf16) ----------
__global__ __launch_bounds__(256) void prep_vt(const float* __restrict__ V, u16* __restrict__ Vt) {
    __shared__ float tile[64][65];
    int t = threadIdx.x;
    int n0 = blockIdx.x * 64;
    int d0 = blockIdx.y * 64;
    int tr = t >> 4, tc = t & 15;
#pragma unroll
    for (int p = 0; p < 4; ++p) {
        int n = p * 16 + tr;
        f32x4 v = *(const f32x4*)(V + (size_t)(n0 + n) * 512 + d0 + tc * 4);
#pragma unroll
        for (int j = 0; j < 4; ++j) tile[n][tc * 4 + j] = v[j];
    }
    __syncthreads();
#pragma unroll
    for (int p = 0; p < 4; ++p) {
        int d = p * 16 + tr;
        u16x4 o;
#pragma unroll
        for (int j = 0; j < 4; ++j) o[j] = f2bf(tile[tc * 4 + j][d]);
        *(u16x4*)(Vt + (size_t)(d0 + d) * 8192 + n0 + tc * 4) = o;
    }
}

// ---------- flash attention: BM=64, KVBLK=64, key-split 2, counted-vmcnt pipeline ----------
// R10 kernel with T3/T4 sync scaffolding: per iter, barrier#1 = vmcnt(16)+s_barrier
// (retires only stage(t); stage(t+1) + vb(t) stay in flight) and barrier#2 =
// lgkmcnt(0)+s_barrier (NO vmem drain -- stage(t+1) crosses it). vb waits are
// compiler-emitted counted vmcnt (vb issued before stage(t+1), FIFO).
__global__ __launch_bounds__(512) void flash_kernel(
    const u16* __restrict__ Qs, const u16* __restrict__ Kb, const u16* __restrict__ Vt,
    float* __restrict__ Opart, float* __restrict__ lpart) {
    __shared__ __align__(16) u16 lds_k[2][64 * 512];  // 128 KB, 16B-chunk XOR swizzle
    __shared__ __align__(16) u16 lds_p[2][64 * 64];   // 16 KB P ping-pong, swizzled
    __shared__ float s_l[2][64];

    const int tid = threadIdx.x;
    const int wid = tid >> 6;
    const int lane = tid & 63;
    const int lo = lane & 15;
    const int hi = lane >> 4;
    const int mi = wid >> 1;    // S-phase row strip (4 x 16 rows)
    const int nj = wid & 1;     // S-phase key half (2 x 32 keys)

    // same-XCD blocks share a key-split (L2 reuse of the K/V stream)
    const int bx = blockIdx.x;
    const int x = bx & 7;
    const int g = bx >> 3;
    const int ks = x >> 2;
    const int mtile = g * 4 + (x & 3);
    const int key0 = ks * 4096;

    // Q fragments (B-operand of swapped S-MFMA): 16 rows, col=lo, k=hi*8+j per kt. 64 VGPR.
    bf16x8 qf[16];
    {
        const u16* qrow = Qs + (size_t)(mtile * 64 + mi * 16 + lo) * 512 + hi * 8;
#pragma unroll
        for (int kt = 0; kt < 16; ++kt) qf[kt] = *(const bf16x8*)(qrow + kt * 32);
    }

    f32x4 o[4][4];
#pragma unroll
    for (int a = 0; a < 4; ++a)
#pragma unroll
        for (int b = 0; b < 4; ++b) o[a][b] = (f32x4){0.f, 0.f, 0.f, 0.f};
    float lsum = 0.f;
    bf16x8 vb[4][2];  // V frags for tile t, consumed by PV at iter t+1 (single buffer)

    // S-read addressing (verified): chunk(kt) = (kt*4+hi) ^ (krow&7), krow = nj*32+lo
    const int cbase = ((hi ^ (lo & 3)) + ((lo >> 2) & 1) * 4) * 8;
    const int rowA = (nj * 32 + lo) * 512;

    // P-write addressing (verified): row = mi*16+lo; key chunks nj*4+(hi>>1) / +2, XOR row&7
    const int qrow = mi * 16 + lo;
    const int ch0 = ((nj * 4 + (hi >> 1)) ^ (qrow & 7));
    const int ch1 = ((nj * 4 + 2 + (hi >> 1)) ^ (qrow & 7));
    const int pw0 = qrow * 64 + (ch0 << 3) + (hi & 1) * 4;
    const int pw1 = qrow * 64 + (ch1 << 3) + (hi & 1) * 4;

#define STAGE_K(IT, BUF)                                                            \
    {                                                                               \
        const u16* kb_ = Kb + (size_t)(key0 + (IT) * 64) * 512;                     \
        _Pragma("unroll") for (int r8_ = 0; r8_ < 8; ++r8_) {                       \
            int row_ = (wid << 3) + r8_;                                            \
            gload_lds16(kb_ + (size_t)row_ * 512 + ((lane ^ (row_ & 7)) << 3),      \
                        &lds_k[BUF][row_ * 512]);                                   \
        }                                                                           \
    }

// 4 independent MFMA chains (depth 8 each)
#define S_COMPUTE(BUF, S0A, S0B, S1A, S1B)                                          \
    {                                                                               \
        const u16* kb = &lds_k[BUF][0];                                             \
        const u16* pAe = kb + rowA + cbase;                                         \
        const u16* pAo = kb + rowA + (cbase ^ 32);                                  \
        const u16* pBe = pAe + 16 * 512;                                            \
        const u16* pBo = pAo + 16 * 512;                                            \
        _Pragma("unroll") for (int kt2 = 0; kt2 < 8; ++kt2) {                       \
            bf16x8 ae = *(const bf16x8*)(pAe + kt2 * 64);                           \
            bf16x8 be = *(const bf16x8*)(pBe + kt2 * 64);                           \
            bf16x8 ao = *(const bf16x8*)(pAo + kt2 * 64);                           \
            bf16x8 bo = *(const bf16x8*)(pBo + kt2 * 64);                           \
            S0A = MFMA16(ae, qf[2 * kt2], S0A);                                     \
            S1A = MFMA16(be, qf[2 * kt2], S1A);                                     \
            S0B = MFMA16(ao, qf[2 * kt2 + 1], S0B);                                 \
            S1B = MFMA16(bo, qf[2 * kt2 + 1], S1B);                                 \
        }                                                                           \
    }

#define PV_STEP(PBUF)                                                               \
    {                                                                               \
        _Pragma("unroll") for (int mt = 0; mt < 4; ++mt) {                          \
            int m = mt * 16 + lo;                                                   \
            int c0 = hi ^ (m & 7);                                                  \
            int c1 = (4 + hi) ^ (m & 7);                                            \
            bf16x8 pa0 = *(const bf16x8*)(&lds_p[PBUF][m * 64 + c0 * 8]);           \
            bf16x8 pa1 = *(const bf16x8*)(&lds_p[PBUF][m * 64 + c1 * 8]);           \
            _Pragma("unroll") for (int nt = 0; nt < 4; ++nt) {                      \
                f32x4 c_ = o[mt][nt];                                               \
                c_ = MFMA16(pa0, vb[nt][0], c_);                                    \
                c_ = MFMA16(pa1, vb[nt][1], c_);                                    \
                o[mt][nt] = c_;                                                     \
            }                                                                       \
        }                                                                           \
    }

#define EXP_PW(S0, S1, PBUF)                                                        \
    {                                                                               \
        u16x4 w0, w1;                                                               \
        _Pragma("unroll") for (int r = 0; r < 4; ++r) {                             \
            float p0 = __expf((S0)[r]);                                             \
            float p1 = __expf((S1)[r]);                                             \
            lsum += p0 + p1;                                                        \
            w0[r] = f2bf(p0);                                                       \
            w1[r] = f2bf(p1);                                                       \
        }                                                                           \
        *(u16x4*)(&lds_p[PBUF][pw0]) = w0;                                          \
        *(u16x4*)(&lds_p[PBUF][pw1]) = w1;                                          \
    }

#define VB_LOAD(T)                                                                  \
    {                                                                               \
        _Pragma("unroll") for (int nt = 0; nt < 4; ++nt) {                          \
            const u16* vrow = Vt + (size_t)(wid * 64 + nt * 16 + lo) * 8192 +       \
                              key0 + (T) * 64 + hi * 8;                             \
            vb[nt][0] = *(const bf16x8*)(vrow);                                     \
            vb[nt][1] = *(const bf16x8*)(vrow + 32);                                \
        }                                                                           \
    }

    // prologue: K(0) -> buf0; one-time full drain
    STAGE_K(0, 0)
    asm volatile("s_waitcnt vmcnt(0)\n\ts_barrier" ::: "memory");

    // iter 0 (no PV): vb(0) then stage(1); S(0) reads already-valid buf0
    {
        VB_LOAD(0)
        asm volatile("" ::: "memory");  // pin issue order: vb(0) before stage(1)
        STAGE_K(1, 1)
        f32x4 s0a = {0.f, 0.f, 0.f, 0.f}, s0b = s0a, s1a = s0a, s1b = s0a;
        __builtin_amdgcn_s_setprio(1);
        S_COMPUTE(0, s0a, s0b, s1a, s1b)
        __builtin_amdgcn_s_setprio(0);
        f32x4 s0 = s0a + s0b, s1 = s1a + s1b;
        EXP_PW(s0, s1, 0)
        asm volatile("s_waitcnt lgkmcnt(0)\n\ts_barrier" ::: "memory");  // P(0) visible; stage(1)+vb(0) fly
    }

    for (int t = 1; t < 63; ++t) {
        const int cur = t & 1;
        // PV(t-1): lds_p[cur^1] + vb(t-1); compiler emits counted vmcnt for vb regs
        __builtin_amdgcn_s_setprio(1);
        PV_STEP(cur ^ 1)
        __builtin_amdgcn_s_setprio(0);
        VB_LOAD(t)
        asm volatile("" ::: "memory");  // pin: vb(t) before stage(t+1) (FIFO count)
        STAGE_K(t + 1, cur ^ 1)
        // barrier#1: stage(t) retired globally -> lds_k[cur] valid; 16 newer ops stay in flight
        asm volatile("s_waitcnt vmcnt(16)\n\ts_barrier" ::: "memory");
        f32x4 s0a = {0.f, 0.f, 0.f, 0.f}, s0b = s0a, s1a = s0a, s1b = s0a;
        __builtin_amdgcn_s_setprio(1);
        S_COMPUTE(cur, s0a, s0b, s1a, s1b)
        __builtin_amdgcn_s_setprio(0);
        f32x4 s0 = s0a + s0b, s1 = s1a + s1b;
        EXP_PW(s0, s1, cur)
        // barrier#2: P(t) visible; NO vmem drain -- stage(t+1) crosses into next iter
        asm volatile("s_waitcnt lgkmcnt(0)\n\ts_barrier" ::: "memory");
    }

    // peeled t=63: no stage(64)
    {
        __builtin_amdgcn_s_setprio(1);
        PV_STEP(0)   // PV(62): cur=1 -> cur^1=0
        __builtin_amdgcn_s_setprio(0);
        VB_LOAD(63)
        // outstanding: stage(63)[8] + vb(63)[8]; retire stage(63)
        asm volatile("s_waitcnt vmcnt(8)\n\ts_barrier" ::: "memory");
        f32x4 s0a = {0.f, 0.f, 0.f, 0.f}, s0b = s0a, s1a = s0a, s1b = s0a;
        __builtin_amdgcn_s_setprio(1);
        S_COMPUTE(1, s0a, s0b, s1a, s1b)
        __builtin_amdgcn_s_setprio(0);
        f32x4 s0 = s0a + s0b, s1 = s1a + s1b;
        EXP_PW(s0, s1, 1)
        asm volatile("s_waitcnt lgkmcnt(0)\n\ts_barrier" ::: "memory");
    }

    // epilogue PV for tile 63 (P in lds_p[1], vb holds V(63); compiler waits vb)
    __builtin_amdgcn_s_setprio(1);
    PV_STEP(1)
    __builtin_amdgcn_s_setprio(0);

    // ---- epilogue: lsum covers wave's 32 keys for qrow; reduce over hi lanes ----
    lsum += __shfl_xor(lsum, 16);
    lsum += __shfl_xor(lsum, 32);
    if (lane < 16) s_l[nj][qrow] = lsum;
    __syncthreads();

    const int lb = mtile * 2 + ks;  // logical partial index
    {
        float* Ob = Opart + (size_t)lb * (64 * 512);
#pragma unroll
        for (int mt = 0; mt < 4; ++mt)
#pragma unroll
            for (int nt = 0; nt < 4; ++nt)
#pragma unroll
                for (int r = 0; r < 4; ++r) {
                    int row = mt * 16 + hi * 4 + r;
                    int col = wid * 64 + nt * 16 + lo;
                    Ob[row * 512 + col] = o[mt][nt][r];
                }
        if (tid < 64) {
            lpart[lb * 64 + tid] = s_l[0][tid] + s_l[1][tid];
        }
    }
}

// ---------- combine the 2 key-split partials: out = (O0+O1)/(l0+l1) ----------
__global__ __launch_bounds__(256) void combine_kernel(const float* __restrict__ Opart,
                                                      const float* __restrict__ lpart,
                                                      float* __restrict__ out) {
    int i = blockIdx.x * 256 + threadIdx.x;  // float4 index; 8192*512/4 = 1048576 total
    int row = i >> 7;
    int c4 = i & 127;
    int mtile = row >> 6, rl = row & 63;
    int b0 = mtile * 2, b1 = b0 + 1;
    float inv = 1.0f / (lpart[b0 * 64 + rl] + lpart[b1 * 64 + rl]);
    f32x4 a = *(const f32x4*)(Opart + (size_t)b0 * 32768 + rl * 512 + c4 * 4);
    f32x4 b = *(const f32x4*)(Opart + (size_t)b1 * 32768 + rl * 512 + c4 * 4);
    f32x4 r = (a + b) * inv;
    *(f32x4*)(out + (size_t)row * 512 + c4 * 4) = r;
}

extern "C" void kernel_launch(void* const* d_in, const int* in_sizes, int n_in,
                              void* d_out, int out_size, void* d_ws, size_t ws_size,
                              hipStream_t stream) {
    const float* Q = (const float*)d_in[0];
    const float* K = (const float*)d_in[1];
    const float* V = (const float*)d_in[2];
    float* out = (float*)d_out;
    char* ws = (char*)d_ws;

    // ws layout (bytes): Qs 8M | Kb 8M | Vt 8M | Opart 32M | lpart 64K
    u16* Qs = (u16*)(ws + 0);
    u16* Kb = (u16*)(ws + 8388608);
    u16* Vt = (u16*)(ws + 16777216);
    float* Op = (float*)(ws + 25165824);
    float* lp = (float*)(ws + 58720256);

    const float scale = 0.08838834764831845f;  // 2 / sqrt(512): softmax(s)^2 renorm == softmax(2s)
    cvt_kernel<<<4096, 256, 0, stream>>>(Q, Qs, 1048576, scale);
    cvt_kernel<<<4096, 256, 0, stream>>>(K, Kb, 1048576, 1.0f);
    prep_vt<<<dim3(128, 8), 256, 0, stream>>>(V, Vt);
    flash_kernel<<<256, 512, 0, stream>>>(Qs, Kb, Vt, Op, lp);
    combine_kernel<<<4096, 256, 0, stream>>>(Op, lp, out);
}